// Round 2
// baseline (40758.322 us; speedup 1.0000x reference)
//
#include <hip/hip_runtime.h>
#include <cstdint>

// 2-layer GRU stack, B=64 T=512 D=H=1024 fp32, length-masked.
//   - all matmuls via bf16 hi/lo split (bf16x3 MFMA, ~fp32 accuracy)
//   - time chunked (TC=32, 16 chunks) to keep workspace ~97 MB
//   - per chunk: splitX -> GEMM0 -> rec0 -> GEMM1 -> rec1(out)
//   - recurrent kernel: 256 wgs x 1 wave, global spin barrier per step

typedef unsigned short u16;
typedef __bf16 bf16x8 __attribute__((ext_vector_type(8)));
typedef float f32x4 __attribute__((ext_vector_type(4)));

#define B_   64
#define T_   512
#define D_   1024
#define H_   1024
#define N3_  3072
#define TC_  32
#define NCH_ 16
#define MROWS_ (B_ * TC_)   // 2048 rows per chunk GEMM

#define MFMA(a, b, c) __builtin_amdgcn_mfma_f32_16x16x32_bf16((a), (b), (c), 0, 0, 0)

static __device__ __forceinline__ u16 f2bf(float x) {
  unsigned u = __float_as_uint(x);
  u += 0x7FFFu + ((u >> 16) & 1u);   // RNE
  return (u16)(u >> 16);
}
static __device__ __forceinline__ float bf2f(u16 s) {
  return __uint_as_float(((unsigned)s) << 16);
}

// ------------------------------------------------------------- init state
__global__ void init_ws(u16* s0h, u16* s0l, u16* s1h, u16* s1l,
                        unsigned* bars) {
  int i = blockIdx.x * blockDim.x + threadIdx.x;
  if (i < B_ * H_) { s0h[i] = 0; s0l[i] = 0; s1h[i] = 0; s1l[i] = 0; }
  if (i < 2 * NCH_ * 32) bars[i] = 0;
}

// ------------------------------------------------- chunk X split (time-major)
// XCh row m = tl*B + b  <-  x[b][t0+tl][:]
__global__ void split_x_chunk(const float* __restrict__ x, int t0,
                              u16* __restrict__ hi, u16* __restrict__ lo) {
  int i = blockIdx.x * blockDim.x + threadIdx.x;  // float4 index, 524288 total
  int m = i >> 8;          // D/4 = 256 float4 per row
  int c = i & 255;
  int tl = m >> 6;         // B_ = 64
  int b = m & 63;
  float4 v = ((const float4*)x)[((size_t)b * T_ + t0 + tl) * 256 + c];
  u16 h0 = f2bf(v.x), h1 = f2bf(v.y), h2 = f2bf(v.z), h3 = f2bf(v.w);
  u16 g0 = f2bf(v.x - bf2f(h0)), g1 = f2bf(v.y - bf2f(h1));
  u16 g2 = f2bf(v.z - bf2f(h2)), g3 = f2bf(v.w - bf2f(h3));
  uint2 ph, pl;
  ph.x = (unsigned)h0 | ((unsigned)h1 << 16);
  ph.y = (unsigned)h2 | ((unsigned)h3 << 16);
  pl.x = (unsigned)g0 | ((unsigned)g1 << 16);
  pl.y = (unsigned)g2 | ((unsigned)g3 << 16);
  *(uint2*)(hi + (size_t)i * 4) = ph;
  *(uint2*)(lo + (size_t)i * 4) = pl;
}

// ------------------------------------------- weight transpose + split
// src [1024][3072] f32 -> dst [3072][1024] bf16 hi/lo
__global__ void transpose_split(const float* __restrict__ src, u16* __restrict__ dhi,
                                u16* __restrict__ dlo) {
  __shared__ float tile[32][33];
  const int tx = threadIdx.x, ty = threadIdx.y;  // 32 x 8
  const int n0 = blockIdx.x * 32, k0 = blockIdx.y * 32;
  #pragma unroll
  for (int i = 0; i < 4; ++i)
    tile[ty + 8 * i][tx] = src[(size_t)(k0 + ty + 8 * i) * N3_ + n0 + tx];
  __syncthreads();
  #pragma unroll
  for (int i = 0; i < 4; ++i) {
    float v = tile[tx][ty + 8 * i];
    size_t o = (size_t)(n0 + ty + 8 * i) * 1024 + k0 + tx;
    u16 h = f2bf(v);
    dhi[o] = h;
    dlo[o] = f2bf(v - bf2f(h));
  }
}

// ------------------------------------------------------- chunk GEMM (bf16x3)
// C[2048][3072] = A[2048][1024] @ B^T[3072][1024]^T + bias
__global__ __launch_bounds__(256, 1) void gemm_bf16x3(
    const u16* __restrict__ Ahi, const u16* __restrict__ Alo,
    const u16* __restrict__ Bhi, const u16* __restrict__ Blo,
    const float* __restrict__ bias, float* __restrict__ C) {
  __shared__ u16 lds[4 * 128 * 64];  // 64 KB, XOR-swizzled tiles [128][64]
  u16* ldsAh = lds;
  u16* ldsAl = lds + 128 * 64;
  u16* ldsBh = lds + 2 * 128 * 64;
  u16* ldsBl = lds + 3 * 128 * 64;

  const int tid = threadIdx.x;
  const int wave = tid >> 6, lane = tid & 63;
  const int l15 = lane & 15, l4 = lane >> 4;
  const int wm = wave >> 1, wn = wave & 1;  // 2x2 waves, 64x64 each
  const int m0 = blockIdx.y * 128, n0 = blockIdx.x * 128;

  f32x4 acc[4][4];
  f32x4 zero = {0.f, 0.f, 0.f, 0.f};
  #pragma unroll
  for (int i = 0; i < 4; ++i)
    #pragma unroll
    for (int j = 0; j < 4; ++j) acc[i][j] = zero;

  for (int kt = 0; kt < 16; ++kt) {  // K = 16 * 64
    #pragma unroll
    for (int q = 0; q < 4; ++q) {
      int chunk = q * 256 + tid;  // 1024 16B-chunks per tile
      int row = chunk >> 3, cc = chunk & 7;
      int sc = cc ^ (row & 7);
      size_t ga = (size_t)(m0 + row) * 1024 + kt * 64 + cc * 8;
      size_t gb = (size_t)(n0 + row) * 1024 + kt * 64 + cc * 8;
      int lo_ = row * 64 + sc * 8;
      *(uint4*)(ldsAh + lo_) = *(const uint4*)(Ahi + ga);
      *(uint4*)(ldsAl + lo_) = *(const uint4*)(Alo + ga);
      *(uint4*)(ldsBh + lo_) = *(const uint4*)(Bhi + gb);
      *(uint4*)(ldsBl + lo_) = *(const uint4*)(Blo + gb);
    }
    __syncthreads();
    #pragma unroll
    for (int kk = 0; kk < 2; ++kk) {
      bf16x8 ah[4], al[4], bh[4], bl[4];
      #pragma unroll
      for (int mt = 0; mt < 4; ++mt) {
        int row = wm * 64 + mt * 16 + l15;
        int off = row * 64 + ((4 * kk + l4) ^ (row & 7)) * 8;
        ah[mt] = *(const bf16x8*)(ldsAh + off);
        al[mt] = *(const bf16x8*)(ldsAl + off);
      }
      #pragma unroll
      for (int nt = 0; nt < 4; ++nt) {
        int row = wn * 64 + nt * 16 + l15;
        int off = row * 64 + ((4 * kk + l4) ^ (row & 7)) * 8;
        bh[nt] = *(const bf16x8*)(ldsBh + off);
        bl[nt] = *(const bf16x8*)(ldsBl + off);
      }
      #pragma unroll
      for (int mt = 0; mt < 4; ++mt)
        #pragma unroll
        for (int nt = 0; nt < 4; ++nt) {
          acc[mt][nt] = MFMA(ah[mt], bh[nt], acc[mt][nt]);
          acc[mt][nt] = MFMA(ah[mt], bl[nt], acc[mt][nt]);
          acc[mt][nt] = MFMA(al[mt], bh[nt], acc[mt][nt]);
        }
    }
    __syncthreads();
  }
  #pragma unroll
  for (int nt = 0; nt < 4; ++nt) {
    int col = n0 + wn * 64 + nt * 16 + l15;
    float bv = bias[col];
    #pragma unroll
    for (int mt = 0; mt < 4; ++mt) {
      int rowb = m0 + wm * 64 + mt * 16 + 4 * l4;
      #pragma unroll
      for (int r = 0; r < 4; ++r)
        C[(size_t)(rowb + r) * N3_ + col] = acc[mt][nt][r] + bv;
    }
  }
}

// ------------------------------------------------ chunk recurrent GRU pass
// 256 wgs x 64 thr; wg = colgrp + 64*mtile (4 wgs sharing weights -> same XCD).
// mx rows tl*B+b; Hh/Hl [TC][B][H]; Sh/Sl [B][H] carry state.
__global__ __launch_bounds__(64, 1) void gru_rec_chunk(
    const float* __restrict__ mx, const u16* __restrict__ wTh,
    const u16* __restrict__ wTl, const float* __restrict__ bias,
    const int* __restrict__ lengths, u16* __restrict__ Sh, u16* __restrict__ Sl,
    u16* __restrict__ Hh, u16* __restrict__ Hl, float* __restrict__ outF32,
    unsigned* __restrict__ bar, int t0) {
  const int wg = blockIdx.x;
  const int colgrp = wg & 63, mtile = wg >> 6;
  const int lane = threadIdx.x;
  const int l15 = lane & 15, l4 = lane >> 4;
  const int koff = 8 * l4;
  const int arow = mtile * 16 + l15;   // batch row for A-fragments
  const int ccol = colgrp * 16 + l15;  // output column

  const u16* bp0h = wTh + ((size_t)(0 * 1024 + ccol)) * 1024 + koff;
  const u16* bp0l = wTl + ((size_t)(0 * 1024 + ccol)) * 1024 + koff;
  const u16* bp1h = wTh + ((size_t)(1 * 1024 + ccol)) * 1024 + koff;
  const u16* bp1l = wTl + ((size_t)(1 * 1024 + ccol)) * 1024 + koff;
  const u16* bp2h = wTh + ((size_t)(2 * 1024 + ccol)) * 1024 + koff;
  const u16* bp2l = wTl + ((size_t)(2 * 1024 + ccol)) * 1024 + koff;

  const float bz = bias[ccol], br = bias[1024 + ccol], bh = bias[2048 + ccol];
  const int brow = mtile * 16 + 4 * l4;
  int lens[4];
  #pragma unroll
  for (int r = 0; r < 4; ++r) lens[r] = lengths[brow + r];

  const f32x4 zero = {0.f, 0.f, 0.f, 0.f};

  #pragma unroll 1
  for (int tl = 0; tl < TC_; ++tl) {
    const u16* Ah = (tl == 0) ? Sh : (Hh + (size_t)(tl - 1) * B_ * H_);
    const u16* Al = (tl == 0) ? Sl : (Hl + (size_t)(tl - 1) * B_ * H_);
    f32x4 a0 = zero, a1 = zero, a2 = zero;
    {
      const u16* aH = Ah + (size_t)arow * H_ + koff;
      const u16* aL = Al + (size_t)arow * H_ + koff;
      #pragma unroll 4
      for (int ks = 0; ks < 32; ++ks) {
        bf16x8 vah = *(const bf16x8*)(aH + ks * 32);
        bf16x8 val = *(const bf16x8*)(aL + ks * 32);
        bf16x8 w0h = *(const bf16x8*)(bp0h + ks * 32);
        bf16x8 w0l = *(const bf16x8*)(bp0l + ks * 32);
        bf16x8 w1h = *(const bf16x8*)(bp1h + ks * 32);
        bf16x8 w1l = *(const bf16x8*)(bp1l + ks * 32);
        bf16x8 w2h = *(const bf16x8*)(bp2h + ks * 32);
        bf16x8 w2l = *(const bf16x8*)(bp2l + ks * 32);
        a0 = MFMA(vah, w0h, a0); a0 = MFMA(vah, w0l, a0); a0 = MFMA(val, w0h, a0);
        a1 = MFMA(vah, w1h, a1); a1 = MFMA(vah, w1l, a1); a1 = MFMA(val, w1h, a1);
        a2 = MFMA(vah, w2h, a2); a2 = MFMA(vah, w2l, a2); a2 = MFMA(val, w2h, a2);
      }
    }
    const int t = t0 + tl;
    #pragma unroll
    for (int r = 0; r < 4; ++r) {
      int b = brow + r;
      size_t mrow = ((size_t)tl * B_ + b) * N3_;
      float xz = mx[mrow + ccol];
      float xr = mx[mrow + 1024 + ccol];
      float xh = mx[mrow + 2048 + ccol];
      float hz = a0[r] + bz, hr = a1[r] + br, hhv = a2[r] + bh;
      float z = 1.f / (1.f + __expf(-(xz + hz)));
      float rg = 1.f / (1.f + __expf(-(xr + hr)));
      float ct = xh + rg * hhv;
      float e2 = __expf(2.f * ct);
      float cand = 1.f - 2.f / (e2 + 1.f);  // tanh(ct)
      size_t poff = (size_t)b * H_ + ccol;
      float hold = bf2f(Ah[poff]) + bf2f(Al[poff]);
      float hnew = (t < lens[r]) ? (z * hold + (1.f - z) * cand) : hold;
      size_t crow = ((size_t)tl * B_ + b) * H_ + ccol;
      u16 nhi = f2bf(hnew);
      u16 nlo = f2bf(hnew - bf2f(nhi));
      Hh[crow] = nhi;
      Hl[crow] = nlo;
      if (outF32) outF32[((size_t)b * T_ + t) * H_ + ccol] = hnew;
      if (tl == TC_ - 1) { Sh[poff] = nhi; Sl[poff] = nlo; }
    }
    if (tl != TC_ - 1) {
      __threadfence();
      if (lane == 0)
        __hip_atomic_fetch_add(bar, 1u, __ATOMIC_ACQ_REL, __HIP_MEMORY_SCOPE_AGENT);
      unsigned target = 256u * (unsigned)(tl + 1);
      while (__hip_atomic_load(bar, __ATOMIC_ACQUIRE, __HIP_MEMORY_SCOPE_AGENT) < target)
        __builtin_amdgcn_s_sleep(2);
      __threadfence();
    }
  }
}

// ----------------------------------------------------------------- launch
extern "C" void kernel_launch(void* const* d_in, const int* in_sizes, int n_in,
                              void* d_out, int out_size, void* d_ws, size_t ws_size,
                              hipStream_t stream) {
  (void)in_sizes; (void)n_in; (void)out_size; (void)ws_size;
  const float* x      = (const float*)d_in[0];
  const int* lengths  = (const int*)d_in[1];
  const float* k0     = (const float*)d_in[2];
  const float* rk0    = (const float*)d_in[3];
  const float* b0     = (const float*)d_in[4];
  const float* k1     = (const float*)d_in[5];
  const float* rk1    = (const float*)d_in[6];
  const float* b1     = (const float*)d_in[7];
  float* out = (float*)d_out;
  char* ws = (char*)d_ws;

  const size_t WB = (size_t)N3_ * 1024 * 2;      // 6,291,456 B
  const size_t XB = (size_t)MROWS_ * 1024 * 2;   // 4,194,304 B
  size_t off = 0;
  u16* k0Th  = (u16*)(ws + off); off += WB;
  u16* k0Tl  = (u16*)(ws + off); off += WB;
  u16* rk0Th = (u16*)(ws + off); off += WB;
  u16* rk0Tl = (u16*)(ws + off); off += WB;
  u16* k1Th  = (u16*)(ws + off); off += WB;
  u16* k1Tl  = (u16*)(ws + off); off += WB;
  u16* rk1Th = (u16*)(ws + off); off += WB;
  u16* rk1Tl = (u16*)(ws + off); off += WB;
  u16* XCh   = (u16*)(ws + off); off += XB;
  u16* XCl   = (u16*)(ws + off); off += XB;
  float* MX  = (float*)(ws + off); off += (size_t)MROWS_ * N3_ * 4;  // 25.2 MB
  u16* H0h   = (u16*)(ws + off); off += XB;
  u16* H0l   = (u16*)(ws + off); off += XB;
  u16* H1h   = (u16*)(ws + off); off += XB;
  u16* H1l   = (u16*)(ws + off); off += XB;
  u16* S0h   = (u16*)(ws + off); off += (size_t)B_ * H_ * 2;
  u16* S0l   = (u16*)(ws + off); off += (size_t)B_ * H_ * 2;
  u16* S1h   = (u16*)(ws + off); off += (size_t)B_ * H_ * 2;
  u16* S1l   = (u16*)(ws + off); off += (size_t)B_ * H_ * 2;
  unsigned* bars = (unsigned*)(ws + off); off += 2 * NCH_ * 32 * 4;
  // total ~97 MB

  init_ws<<<256, 256, 0, stream>>>(S0h, S0l, S1h, S1l, bars);

  dim3 tb(32, 8), tg(96, 32);
  transpose_split<<<tg, tb, 0, stream>>>(k0,  k0Th,  k0Tl);
  transpose_split<<<tg, tb, 0, stream>>>(rk0, rk0Th, rk0Tl);
  transpose_split<<<tg, tb, 0, stream>>>(k1,  k1Th,  k1Tl);
  transpose_split<<<tg, tb, 0, stream>>>(rk1, rk1Th, rk1Tl);

  for (int c = 0; c < NCH_; ++c) {
    int t0 = c * TC_;
    split_x_chunk<<<2048, 256, 0, stream>>>(x, t0, XCh, XCl);
    gemm_bf16x3<<<dim3(24, 16), 256, 0, stream>>>(XCh, XCl, k0Th, k0Tl, b0, MX);
    gru_rec_chunk<<<256, 64, 0, stream>>>(MX, rk0Th, rk0Tl, b0 + N3_, lengths,
                                          S0h, S0l, H0h, H0l, nullptr,
                                          bars + c * 32, t0);
    gemm_bf16x3<<<dim3(24, 16), 256, 0, stream>>>(H0h, H0l, k1Th, k1Tl, b1, MX);
    gru_rec_chunk<<<256, 64, 0, stream>>>(MX, rk1Th, rk1Tl, b1 + N3_, lengths,
                                          S1h, S1l, H1h, H1l, out,
                                          bars + (NCH_ + c) * 32, t0);
  }
}

// Round 3
// 15470.279 us; speedup vs baseline: 2.6346x; 2.6346x over previous
//
#include <hip/hip_runtime.h>
#include <cstdint>

// 2-layer GRU stack, B=64 T=512 D=H=1024 fp32, length-masked.
//   - matmuls via bf16 hi/lo split (bf16x3 MFMA, ~fp32 accuracy)
//   - time chunked (TC=32, 16 chunks), workspace ~97 MB
//   - rec kernel v2: 256 wgs x 4 waves; recurrent weights in REGISTERS
//     (192 VGPR/wave, loaded once), h_prev staged in LDS, per-mtile
//     relaxed-poll grid barriers (4 independent 64-wg domains)

typedef unsigned short u16;
typedef __bf16 bf16x8 __attribute__((ext_vector_type(8)));
typedef float f32x4 __attribute__((ext_vector_type(4)));

#define B_   64
#define T_   512
#define D_   1024
#define H_   1024
#define N3_  3072
#define TC_  32
#define NCH_ 16
#define MROWS_ (B_ * TC_)   // 2048 rows per chunk GEMM

#define MFMA(a, b, c) __builtin_amdgcn_mfma_f32_16x16x32_bf16((a), (b), (c), 0, 0, 0)

static __device__ __forceinline__ u16 f2bf(float x) {
  unsigned u = __float_as_uint(x);
  u += 0x7FFFu + ((u >> 16) & 1u);   // RNE
  return (u16)(u >> 16);
}
static __device__ __forceinline__ float bf2f(u16 s) {
  return __uint_as_float(((unsigned)s) << 16);
}

// ------------------------------------------------------------- init state
__global__ void init_ws(u16* s0h, u16* s0l, u16* s1h, u16* s1l,
                        unsigned* bars) {
  int i = blockIdx.x * blockDim.x + threadIdx.x;
  if (i < B_ * H_) { s0h[i] = 0; s0l[i] = 0; s1h[i] = 0; s1l[i] = 0; }
  if (i < 2 * NCH_ * 256) bars[i] = 0;
}

// ------------------------------------------------- chunk X split (time-major)
__global__ void split_x_chunk(const float* __restrict__ x, int t0,
                              u16* __restrict__ hi, u16* __restrict__ lo) {
  int i = blockIdx.x * blockDim.x + threadIdx.x;  // float4 index, 524288 total
  int m = i >> 8;          // D/4 = 256 float4 per row
  int c = i & 255;
  int tl = m >> 6;         // B_ = 64
  int b = m & 63;
  float4 v = ((const float4*)x)[((size_t)b * T_ + t0 + tl) * 256 + c];
  u16 h0 = f2bf(v.x), h1 = f2bf(v.y), h2 = f2bf(v.z), h3 = f2bf(v.w);
  u16 g0 = f2bf(v.x - bf2f(h0)), g1 = f2bf(v.y - bf2f(h1));
  u16 g2 = f2bf(v.z - bf2f(h2)), g3 = f2bf(v.w - bf2f(h3));
  uint2 ph, pl;
  ph.x = (unsigned)h0 | ((unsigned)h1 << 16);
  ph.y = (unsigned)h2 | ((unsigned)h3 << 16);
  pl.x = (unsigned)g0 | ((unsigned)g1 << 16);
  pl.y = (unsigned)g2 | ((unsigned)g3 << 16);
  *(uint2*)(hi + (size_t)i * 4) = ph;
  *(uint2*)(lo + (size_t)i * 4) = pl;
}

// ------------------------------------------- weight transpose + split
// src [1024][3072] f32 -> dst [3072][1024] bf16 hi/lo
__global__ void transpose_split(const float* __restrict__ src, u16* __restrict__ dhi,
                                u16* __restrict__ dlo) {
  __shared__ float tile[32][33];
  const int tx = threadIdx.x, ty = threadIdx.y;  // 32 x 8
  const int n0 = blockIdx.x * 32, k0 = blockIdx.y * 32;
  #pragma unroll
  for (int i = 0; i < 4; ++i)
    tile[ty + 8 * i][tx] = src[(size_t)(k0 + ty + 8 * i) * N3_ + n0 + tx];
  __syncthreads();
  #pragma unroll
  for (int i = 0; i < 4; ++i) {
    float v = tile[tx][ty + 8 * i];
    size_t o = (size_t)(n0 + ty + 8 * i) * 1024 + k0 + tx;
    u16 h = f2bf(v);
    dhi[o] = h;
    dlo[o] = f2bf(v - bf2f(h));
  }
}

// ------------------------------------------------------- chunk GEMM (bf16x3)
// C[2048][3072] = A[2048][1024] @ B^T[3072][1024]^T + bias
__global__ __launch_bounds__(256, 1) void gemm_bf16x3(
    const u16* __restrict__ Ahi, const u16* __restrict__ Alo,
    const u16* __restrict__ Bhi, const u16* __restrict__ Blo,
    const float* __restrict__ bias, float* __restrict__ C) {
  __shared__ u16 lds[4 * 128 * 64];  // 64 KB, XOR-swizzled tiles [128][64]
  u16* ldsAh = lds;
  u16* ldsAl = lds + 128 * 64;
  u16* ldsBh = lds + 2 * 128 * 64;
  u16* ldsBl = lds + 3 * 128 * 64;

  const int tid = threadIdx.x;
  const int wave = tid >> 6, lane = tid & 63;
  const int l15 = lane & 15, l4 = lane >> 4;
  const int wm = wave >> 1, wn = wave & 1;  // 2x2 waves, 64x64 each
  const int m0 = blockIdx.y * 128, n0 = blockIdx.x * 128;

  f32x4 acc[4][4];
  f32x4 zero = {0.f, 0.f, 0.f, 0.f};
  #pragma unroll
  for (int i = 0; i < 4; ++i)
    #pragma unroll
    for (int j = 0; j < 4; ++j) acc[i][j] = zero;

  for (int kt = 0; kt < 16; ++kt) {  // K = 16 * 64
    #pragma unroll
    for (int q = 0; q < 4; ++q) {
      int chunk = q * 256 + tid;  // 1024 16B-chunks per tile
      int row = chunk >> 3, cc = chunk & 7;
      int sc = cc ^ (row & 7);
      size_t ga = (size_t)(m0 + row) * 1024 + kt * 64 + cc * 8;
      size_t gb = (size_t)(n0 + row) * 1024 + kt * 64 + cc * 8;
      int lo_ = row * 64 + sc * 8;
      *(uint4*)(ldsAh + lo_) = *(const uint4*)(Ahi + ga);
      *(uint4*)(ldsAl + lo_) = *(const uint4*)(Alo + ga);
      *(uint4*)(ldsBh + lo_) = *(const uint4*)(Bhi + gb);
      *(uint4*)(ldsBl + lo_) = *(const uint4*)(Blo + gb);
    }
    __syncthreads();
    #pragma unroll
    for (int kk = 0; kk < 2; ++kk) {
      bf16x8 ah[4], al[4], bh[4], bl[4];
      #pragma unroll
      for (int mt = 0; mt < 4; ++mt) {
        int row = wm * 64 + mt * 16 + l15;
        int off = row * 64 + ((4 * kk + l4) ^ (row & 7)) * 8;
        ah[mt] = *(const bf16x8*)(ldsAh + off);
        al[mt] = *(const bf16x8*)(ldsAl + off);
      }
      #pragma unroll
      for (int nt = 0; nt < 4; ++nt) {
        int row = wn * 64 + nt * 16 + l15;
        int off = row * 64 + ((4 * kk + l4) ^ (row & 7)) * 8;
        bh[nt] = *(const bf16x8*)(ldsBh + off);
        bl[nt] = *(const bf16x8*)(ldsBl + off);
      }
      #pragma unroll
      for (int mt = 0; mt < 4; ++mt)
        #pragma unroll
        for (int nt = 0; nt < 4; ++nt) {
          acc[mt][nt] = MFMA(ah[mt], bh[nt], acc[mt][nt]);
          acc[mt][nt] = MFMA(ah[mt], bl[nt], acc[mt][nt]);
          acc[mt][nt] = MFMA(al[mt], bh[nt], acc[mt][nt]);
        }
    }
    __syncthreads();
  }
  #pragma unroll
  for (int nt = 0; nt < 4; ++nt) {
    int col = n0 + wn * 64 + nt * 16 + l15;
    float bv = bias[col];
    #pragma unroll
    for (int mt = 0; mt < 4; ++mt) {
      int rowb = m0 + wm * 64 + mt * 16 + 4 * l4;
      #pragma unroll
      for (int r = 0; r < 4; ++r)
        C[(size_t)(rowb + r) * N3_ + col] = acc[mt][nt][r] + bv;
    }
  }
}

// ------------------------------------------------ chunk recurrent GRU (v2)
// 256 wgs x 256 thr. wg = colgrp + 64*mtile. Weights in registers (per wave:
// its K-quarter of 3 gates, hi+lo = 48 x bf16x8). h_prev staged in LDS.
// 4 independent per-mtile barrier domains, relaxed polling.
__global__ __launch_bounds__(256, 1) void gru_rec_v2(
    const float* __restrict__ mx, const u16* __restrict__ wTh,
    const u16* __restrict__ wTl, const float* __restrict__ bias,
    const int* __restrict__ lengths, u16* __restrict__ Sh, u16* __restrict__ Sl,
    u16* __restrict__ Hh, u16* __restrict__ Hl, float* __restrict__ outF32,
    unsigned* __restrict__ bars, int t0) {
  __shared__ __align__(16) char lds[77824];
  char* ldsAh = lds;            // [16 rows][2048 B] swizzled (h_prev hi)
  char* ldsAl = lds + 32768;    // lo
  char* ldsRed = lds + 65536;   // reduce: 3 waves x 3 gates x 1KB

  const int bid = blockIdx.x;
  const int colgrp = bid & 63, mtile = bid >> 6;
  const int tid = threadIdx.x;
  const int wave = tid >> 6, lane = tid & 63;
  const int l15 = lane & 15, l4 = lane >> 4;
  const int ccol = colgrp * 16 + l15;
  unsigned* bar = bars + mtile * 64;   // 256B-spaced counters

  // ---- recurrent weights -> registers (once per dispatch)
  const int kbase = wave * 256 + 8 * l4;
  bf16x8 Wh[3][8], Wl[3][8];
  #pragma unroll
  for (int g = 0; g < 3; ++g) {
    const size_t wrow = ((size_t)(g * 1024 + ccol)) * 1024 + kbase;
    #pragma unroll
    for (int ks = 0; ks < 8; ++ks) {
      Wh[g][ks] = *(const bf16x8*)(wTh + wrow + ks * 32);
      Wl[g][ks] = *(const bf16x8*)(wTl + wrow + ks * 32);
    }
  }

  const float bz = bias[ccol], br = bias[1024 + ccol], bh = bias[2048 + ccol];
  const int brow = mtile * 16 + 4 * l4;
  int lens[4];
  #pragma unroll
  for (int r = 0; r < 4; ++r) lens[r] = lengths[brow + r];
  const int grow0 = mtile * 16;

  #pragma unroll 1
  for (int tl = 0; tl < TC_; ++tl) {
    const u16* srcH = (tl == 0) ? Sh : (Hh + (size_t)(tl - 1) * B_ * H_);
    const u16* srcL = (tl == 0) ? Sl : (Hl + (size_t)(tl - 1) * B_ * H_);

    // ---- wave0: prefetch mx + h_old early (consumed after reduce)
    float pxz[4], pxr[4], pxh[4], phold[4];
    if (wave == 0) {
      #pragma unroll
      for (int r = 0; r < 4; ++r) {
        int b = brow + r;
        size_t mrow = ((size_t)tl * B_ + b) * N3_;
        pxz[r] = mx[mrow + ccol];
        pxr[r] = mx[mrow + 1024 + ccol];
        pxh[r] = mx[mrow + 2048 + ccol];
        size_t poff = (size_t)b * H_ + ccol;
        phold[r] = bf2f(srcH[poff]) + bf2f(srcL[poff]);
      }
    }

    // ---- stage h_prev (this mtile's 16 rows) into LDS, XOR-swizzled
    #pragma unroll
    for (int i = 0; i < 8; ++i) {
      int c = i * 256 + tid;       // 2048 chunks of 16B per buffer
      int row = c >> 7, k16 = c & 127;
      int dso = row * 2048 + ((k16 * 16) ^ ((row & 7) << 4));
      size_t go = (size_t)(grow0 + row) * H_ + k16 * 8;
      *(uint4*)(ldsAh + dso) = *(const uint4*)(srcH + go);
      *(uint4*)(ldsAl + dso) = *(const uint4*)(srcL + go);
    }
    __syncthreads();

    // ---- MFMA: 3 gates over this wave's K-quarter (bf16x3)
    f32x4 a0 = {0.f, 0.f, 0.f, 0.f};
    f32x4 a1 = a0, a2 = a0;
    #pragma unroll
    for (int ks = 0; ks < 8; ++ks) {
      int k16 = wave * 32 + ks * 4 + l4;
      int dso = l15 * 2048 + ((k16 * 16) ^ ((l15 & 7) << 4));
      bf16x8 ah = *(const bf16x8*)(ldsAh + dso);
      bf16x8 al = *(const bf16x8*)(ldsAl + dso);
      a0 = MFMA(ah, Wh[0][ks], a0); a0 = MFMA(ah, Wl[0][ks], a0); a0 = MFMA(al, Wh[0][ks], a0);
      a1 = MFMA(ah, Wh[1][ks], a1); a1 = MFMA(ah, Wl[1][ks], a1); a1 = MFMA(al, Wh[1][ks], a1);
      a2 = MFMA(ah, Wh[2][ks], a2); a2 = MFMA(ah, Wl[2][ks], a2); a2 = MFMA(al, Wh[2][ks], a2);
    }

    // ---- cross-wave K-reduce
    if (wave != 0) {
      int rb = (wave - 1) * 3072;
      *(f32x4*)(ldsRed + rb + 0 * 1024 + lane * 16) = a0;
      *(f32x4*)(ldsRed + rb + 1 * 1024 + lane * 16) = a1;
      *(f32x4*)(ldsRed + rb + 2 * 1024 + lane * 16) = a2;
    }
    __syncthreads();

    if (wave == 0) {
      #pragma unroll
      for (int w = 1; w < 4; ++w) {
        int rb = (w - 1) * 3072;
        a0 += *(const f32x4*)(ldsRed + rb + 0 * 1024 + lane * 16);
        a1 += *(const f32x4*)(ldsRed + rb + 1 * 1024 + lane * 16);
        a2 += *(const f32x4*)(ldsRed + rb + 2 * 1024 + lane * 16);
      }
      const int t = t0 + tl;
      #pragma unroll
      for (int r = 0; r < 4; ++r) {
        int b = brow + r;
        float hz = a0[r] + bz, hr = a1[r] + br, hhv = a2[r] + bh;
        float z  = 1.f / (1.f + __expf(-(pxz[r] + hz)));
        float rg = 1.f / (1.f + __expf(-(pxr[r] + hr)));
        float ct = pxh[r] + rg * hhv;
        float e2 = __expf(2.f * ct);
        float cand = 1.f - 2.f / (e2 + 1.f);  // tanh(ct)
        float hnew = (t < lens[r]) ? (z * phold[r] + (1.f - z) * cand) : phold[r];
        size_t crow = ((size_t)tl * B_ + b) * H_ + ccol;
        u16 nhi = f2bf(hnew);
        u16 nlo = f2bf(hnew - bf2f(nhi));
        Hh[crow] = nhi; Hl[crow] = nlo;
        if (outF32) outF32[((size_t)b * T_ + t) * H_ + ccol] = hnew;
        if (tl == TC_ - 1) {
          size_t poff = (size_t)b * H_ + ccol;
          Sh[poff] = nhi; Sl[poff] = nlo;
        }
      }
    }

    // ---- per-mtile grid barrier: release add, relaxed poll, one acq fence
    if (tl != TC_ - 1) {
      if (tid == 0) {
        __hip_atomic_fetch_add(bar, 1u, __ATOMIC_RELEASE, __HIP_MEMORY_SCOPE_AGENT);
        unsigned tgt = 64u * (unsigned)(tl + 1);
        while (__hip_atomic_load(bar, __ATOMIC_RELAXED, __HIP_MEMORY_SCOPE_AGENT) < tgt)
          __builtin_amdgcn_s_sleep(8);
        __threadfence();  // acquire side, once
      }
      __syncthreads();
    }
  }
}

// ----------------------------------------------------------------- launch
extern "C" void kernel_launch(void* const* d_in, const int* in_sizes, int n_in,
                              void* d_out, int out_size, void* d_ws, size_t ws_size,
                              hipStream_t stream) {
  (void)in_sizes; (void)n_in; (void)out_size; (void)ws_size;
  const float* x      = (const float*)d_in[0];
  const int* lengths  = (const int*)d_in[1];
  const float* k0     = (const float*)d_in[2];
  const float* rk0    = (const float*)d_in[3];
  const float* b0     = (const float*)d_in[4];
  const float* k1     = (const float*)d_in[5];
  const float* rk1    = (const float*)d_in[6];
  const float* b1     = (const float*)d_in[7];
  float* out = (float*)d_out;
  char* ws = (char*)d_ws;

  const size_t WB = (size_t)N3_ * 1024 * 2;      // 6,291,456 B
  const size_t XB = (size_t)MROWS_ * 1024 * 2;   // 4,194,304 B
  size_t off = 0;
  u16* k0Th  = (u16*)(ws + off); off += WB;
  u16* k0Tl  = (u16*)(ws + off); off += WB;
  u16* rk0Th = (u16*)(ws + off); off += WB;
  u16* rk0Tl = (u16*)(ws + off); off += WB;
  u16* k1Th  = (u16*)(ws + off); off += WB;
  u16* k1Tl  = (u16*)(ws + off); off += WB;
  u16* rk1Th = (u16*)(ws + off); off += WB;
  u16* rk1Tl = (u16*)(ws + off); off += WB;
  u16* XCh   = (u16*)(ws + off); off += XB;
  u16* XCl   = (u16*)(ws + off); off += XB;
  float* MX  = (float*)(ws + off); off += (size_t)MROWS_ * N3_ * 4;  // 25.2 MB
  u16* H0h   = (u16*)(ws + off); off += XB;
  u16* H0l   = (u16*)(ws + off); off += XB;
  u16* H1h   = (u16*)(ws + off); off += XB;
  u16* H1l   = (u16*)(ws + off); off += XB;
  u16* S0h   = (u16*)(ws + off); off += (size_t)B_ * H_ * 2;
  u16* S0l   = (u16*)(ws + off); off += (size_t)B_ * H_ * 2;
  u16* S1h   = (u16*)(ws + off); off += (size_t)B_ * H_ * 2;
  u16* S1l   = (u16*)(ws + off); off += (size_t)B_ * H_ * 2;
  unsigned* bars = (unsigned*)(ws + off); off += (size_t)2 * NCH_ * 256 * 4;
  // total ~97 MB

  init_ws<<<256, 256, 0, stream>>>(S0h, S0l, S1h, S1l, bars);

  dim3 tb(32, 8), tg(96, 32);
  transpose_split<<<tg, tb, 0, stream>>>(k0,  k0Th,  k0Tl);
  transpose_split<<<tg, tb, 0, stream>>>(rk0, rk0Th, rk0Tl);
  transpose_split<<<tg, tb, 0, stream>>>(k1,  k1Th,  k1Tl);
  transpose_split<<<tg, tb, 0, stream>>>(rk1, rk1Th, rk1Tl);

  for (int c = 0; c < NCH_; ++c) {
    int t0 = c * TC_;
    split_x_chunk<<<2048, 256, 0, stream>>>(x, t0, XCh, XCl);
    gemm_bf16x3<<<dim3(24, 16), 256, 0, stream>>>(XCh, XCl, k0Th, k0Tl, b0, MX);
    gru_rec_v2<<<256, 256, 0, stream>>>(MX, rk0Th, rk0Tl, b0 + N3_, lengths,
                                        S0h, S0l, H0h, H0l, nullptr,
                                        bars + (size_t)c * 256, t0);
    gemm_bf16x3<<<dim3(24, 16), 256, 0, stream>>>(H0h, H0l, k1Th, k1Tl, b1, MX);
    gru_rec_v2<<<256, 256, 0, stream>>>(MX, rk1Th, rk1Tl, b1 + N3_, lengths,
                                        S1h, S1l, H1h, H1l, out,
                                        bars + (size_t)(NCH_ + c) * 256, t0);
  }
}

// Round 4
// 14159.590 us; speedup vs baseline: 2.8785x; 1.0926x over previous
//
#include <hip/hip_runtime.h>
#include <cstdint>

// 2-layer GRU stack, B=64 T=512 D=H=1024 fp32, length-masked.
//   - matmuls via bf16 hi/lo split (bf16x3 MFMA, ~fp32 accuracy)
//   - time chunked (TC=32, 16 chunks), workspace ~93 MB
//   - rec kernel v3: 256 wgs x 4 waves; recurrent weights in REGISTERS;
//     fence-free h exchange: packed u32 h via relaxed-agent (sc1) stores,
//     vmcnt(0)+relaxed atomic flag, relaxed polls. No buffer_wbl2/buffer_inv.

typedef unsigned short u16;
typedef unsigned int u32;
typedef unsigned long long u64;
typedef __bf16 bf16x8 __attribute__((ext_vector_type(8)));
typedef float f32x4 __attribute__((ext_vector_type(4)));

#define B_   64
#define T_   512
#define D_   1024
#define H_   1024
#define N3_  3072
#define TC_  32
#define NCH_ 16
#define MROWS_ (B_ * TC_)   // 2048 rows per chunk GEMM

#define MFMA(a, b, c) __builtin_amdgcn_mfma_f32_16x16x32_bf16((a), (b), (c), 0, 0, 0)

static __device__ __forceinline__ u16 f2bf(float x) {
  unsigned u = __float_as_uint(x);
  u += 0x7FFFu + ((u >> 16) & 1u);   // RNE
  return (u16)(u >> 16);
}
static __device__ __forceinline__ float bf2f(u16 s) {
  return __uint_as_float(((unsigned)s) << 16);
}

// ------------------------------------------------------------- init state
__global__ void init_ws(u32* s0, u32* s1, unsigned* bars) {
  int i = blockIdx.x * blockDim.x + threadIdx.x;
  if (i < B_ * H_) { s0[i] = 0; s1[i] = 0; }
  if (i < 2 * NCH_ * 256) bars[i] = 0;
}

// ------------------------------------------------- chunk X split (time-major)
__global__ void split_x_chunk(const float* __restrict__ x, int t0,
                              u16* __restrict__ hi, u16* __restrict__ lo) {
  int i = blockIdx.x * blockDim.x + threadIdx.x;  // float4 index, 524288 total
  int m = i >> 8;          // D/4 = 256 float4 per row
  int c = i & 255;
  int tl = m >> 6;         // B_ = 64
  int b = m & 63;
  float4 v = ((const float4*)x)[((size_t)b * T_ + t0 + tl) * 256 + c];
  u16 h0 = f2bf(v.x), h1 = f2bf(v.y), h2 = f2bf(v.z), h3 = f2bf(v.w);
  u16 g0 = f2bf(v.x - bf2f(h0)), g1 = f2bf(v.y - bf2f(h1));
  u16 g2 = f2bf(v.z - bf2f(h2)), g3 = f2bf(v.w - bf2f(h3));
  uint2 ph, pl;
  ph.x = (unsigned)h0 | ((unsigned)h1 << 16);
  ph.y = (unsigned)h2 | ((unsigned)h3 << 16);
  pl.x = (unsigned)g0 | ((unsigned)g1 << 16);
  pl.y = (unsigned)g2 | ((unsigned)g3 << 16);
  *(uint2*)(hi + (size_t)i * 4) = ph;
  *(uint2*)(lo + (size_t)i * 4) = pl;
}

// ------------------------------------------- weight transpose + split
__global__ void transpose_split(const float* __restrict__ src, u16* __restrict__ dhi,
                                u16* __restrict__ dlo) {
  __shared__ float tile[32][33];
  const int tx = threadIdx.x, ty = threadIdx.y;  // 32 x 8
  const int n0 = blockIdx.x * 32, k0 = blockIdx.y * 32;
  #pragma unroll
  for (int i = 0; i < 4; ++i)
    tile[ty + 8 * i][tx] = src[(size_t)(k0 + ty + 8 * i) * N3_ + n0 + tx];
  __syncthreads();
  #pragma unroll
  for (int i = 0; i < 4; ++i) {
    float v = tile[tx][ty + 8 * i];
    size_t o = (size_t)(n0 + ty + 8 * i) * 1024 + k0 + tx;
    u16 h = f2bf(v);
    dhi[o] = h;
    dlo[o] = f2bf(v - bf2f(h));
  }
}

// ------------------------------------------------------- chunk GEMM (bf16x3)
__global__ __launch_bounds__(256, 1) void gemm_bf16x3(
    const u16* __restrict__ Ahi, const u16* __restrict__ Alo,
    const u16* __restrict__ Bhi, const u16* __restrict__ Blo,
    const float* __restrict__ bias, float* __restrict__ C) {
  __shared__ u16 lds[4 * 128 * 64];  // 64 KB, XOR-swizzled tiles [128][64]
  u16* ldsAh = lds;
  u16* ldsAl = lds + 128 * 64;
  u16* ldsBh = lds + 2 * 128 * 64;
  u16* ldsBl = lds + 3 * 128 * 64;

  const int tid = threadIdx.x;
  const int wave = tid >> 6, lane = tid & 63;
  const int l15 = lane & 15, l4 = lane >> 4;
  const int wm = wave >> 1, wn = wave & 1;  // 2x2 waves, 64x64 each
  const int m0 = blockIdx.y * 128, n0 = blockIdx.x * 128;

  f32x4 acc[4][4];
  f32x4 zero = {0.f, 0.f, 0.f, 0.f};
  #pragma unroll
  for (int i = 0; i < 4; ++i)
    #pragma unroll
    for (int j = 0; j < 4; ++j) acc[i][j] = zero;

  for (int kt = 0; kt < 16; ++kt) {  // K = 16 * 64
    #pragma unroll
    for (int q = 0; q < 4; ++q) {
      int chunk = q * 256 + tid;
      int row = chunk >> 3, cc = chunk & 7;
      int sc = cc ^ (row & 7);
      size_t ga = (size_t)(m0 + row) * 1024 + kt * 64 + cc * 8;
      size_t gb = (size_t)(n0 + row) * 1024 + kt * 64 + cc * 8;
      int lo_ = row * 64 + sc * 8;
      *(uint4*)(ldsAh + lo_) = *(const uint4*)(Ahi + ga);
      *(uint4*)(ldsAl + lo_) = *(const uint4*)(Alo + ga);
      *(uint4*)(ldsBh + lo_) = *(const uint4*)(Bhi + gb);
      *(uint4*)(ldsBl + lo_) = *(const uint4*)(Blo + gb);
    }
    __syncthreads();
    #pragma unroll
    for (int kk = 0; kk < 2; ++kk) {
      bf16x8 ah[4], al[4], bh[4], bl[4];
      #pragma unroll
      for (int mt = 0; mt < 4; ++mt) {
        int row = wm * 64 + mt * 16 + l15;
        int off = row * 64 + ((4 * kk + l4) ^ (row & 7)) * 8;
        ah[mt] = *(const bf16x8*)(ldsAh + off);
        al[mt] = *(const bf16x8*)(ldsAl + off);
      }
      #pragma unroll
      for (int nt = 0; nt < 4; ++nt) {
        int row = wn * 64 + nt * 16 + l15;
        int off = row * 64 + ((4 * kk + l4) ^ (row & 7)) * 8;
        bh[nt] = *(const bf16x8*)(ldsBh + off);
        bl[nt] = *(const bf16x8*)(ldsBl + off);
      }
      #pragma unroll
      for (int mt = 0; mt < 4; ++mt)
        #pragma unroll
        for (int nt = 0; nt < 4; ++nt) {
          acc[mt][nt] = MFMA(ah[mt], bh[nt], acc[mt][nt]);
          acc[mt][nt] = MFMA(ah[mt], bl[nt], acc[mt][nt]);
          acc[mt][nt] = MFMA(al[mt], bh[nt], acc[mt][nt]);
        }
    }
    __syncthreads();
  }
  #pragma unroll
  for (int nt = 0; nt < 4; ++nt) {
    int col = n0 + wn * 64 + nt * 16 + l15;
    float bv = bias[col];
    #pragma unroll
    for (int mt = 0; mt < 4; ++mt) {
      int rowb = m0 + wm * 64 + mt * 16 + 4 * l4;
      #pragma unroll
      for (int r = 0; r < 4; ++r)
        C[(size_t)(rowb + r) * N3_ + col] = acc[mt][nt][r] + bv;
    }
  }
}

// ------------------------------------------------ chunk recurrent GRU (v3)
// 256 wgs x 256 thr. wg = colgrp + 64*mtile. Weights in registers.
// h exchange: Hpk [TC][B][H] packed u32 (hi<<16|lo), relaxed-agent stores
// (write-through to coherence point); per-mtile flag, relaxed polls; NO
// release/acquire fences anywhere in the loop (mx/weights stay in L2).
__global__ __launch_bounds__(256, 1) void gru_rec_v3(
    const float* __restrict__ mx, const u16* __restrict__ wTh,
    const u16* __restrict__ wTl, const float* __restrict__ bias,
    const int* __restrict__ lengths,
    u32* __restrict__ Spk, u32* __restrict__ Hpk,
    u16* __restrict__ Hh, u16* __restrict__ Hl, float* __restrict__ outF32,
    unsigned* __restrict__ bars, int t0) {
  __shared__ __align__(16) char lds[74752];
  char* ldsP = lds;            // [16 rows][4096 B] packed u32, ^((row&7)<<4)
  char* ldsRed = lds + 65536;  // reduce: 3 waves x 3 gates x 1KB

  const int bid = blockIdx.x;
  const int colgrp = bid & 63, mtile = bid >> 6;
  const int tid = threadIdx.x;
  const int wave = tid >> 6, lane = tid & 63;
  const int l15 = lane & 15, l4 = lane >> 4;
  const int ccol = colgrp * 16 + l15;
  unsigned* bar = bars + mtile * 64;   // 256B-spaced counters
  const int grow0 = mtile * 16;

  // ---- recurrent weights -> registers (once per dispatch)
  const int kbase = wave * 256 + 8 * l4;
  bf16x8 Wh[3][8], Wl[3][8];
  #pragma unroll
  for (int g = 0; g < 3; ++g) {
    const size_t wrow = ((size_t)(g * 1024 + ccol)) * 1024 + kbase;
    #pragma unroll
    for (int ks = 0; ks < 8; ++ks) {
      Wh[g][ks] = *(const bf16x8*)(wTh + wrow + ks * 32);
      Wl[g][ks] = *(const bf16x8*)(wTl + wrow + ks * 32);
    }
  }

  const float bz = bias[ccol], br = bias[1024 + ccol], bh = bias[2048 + ccol];
  const int brow = mtile * 16 + 4 * l4;
  int lens[4];
  #pragma unroll
  for (int r = 0; r < 4; ++r) lens[r] = lengths[brow + r];

  #pragma unroll 1
  for (int tl = 0; tl < TC_; ++tl) {
    const u32* srcPk = (tl == 0) ? Spk : (Hpk + (size_t)(tl - 1) * B_ * H_);

    // ---- wave0: prefetch mx + h_old (L2-resident mx; sc1 h)
    float pxz[4], pxr[4], pxh[4], phold[4];
    if (wave == 0) {
      #pragma unroll
      for (int r = 0; r < 4; ++r) {
        int b = brow + r;
        size_t mrow = ((size_t)tl * B_ + b) * N3_;
        pxz[r] = mx[mrow + ccol];
        pxr[r] = mx[mrow + 1024 + ccol];
        pxh[r] = mx[mrow + 2048 + ccol];
        u32 p = __hip_atomic_load((u32*)(srcPk + (size_t)b * H_ + ccol),
                                  __ATOMIC_RELAXED, __HIP_MEMORY_SCOPE_AGENT);
        phold[r] = bf2f((u16)(p >> 16)) + bf2f((u16)(p & 0xFFFFu));
      }
    }

    // ---- stage packed h (16 rows x 1024 cols x 4B) into LDS, coalesced u64
    #pragma unroll
    for (int i = 0; i < 32; ++i) {
      int o = (i * 256 + tid) * 8;   // byte offset 0..65535
      int row = o >> 12;
      int cb = o & 4095;
      u64 v = __hip_atomic_load(
          (u64*)(srcPk + (size_t)(grow0 + row) * H_ + (cb >> 2)),
          __ATOMIC_RELAXED, __HIP_MEMORY_SCOPE_AGENT);
      *(u64*)(ldsP + row * 4096 + (cb ^ ((row & 7) << 4))) = v;
    }
    __syncthreads();

    // ---- MFMA: 3 gates over this wave's K-quarter (bf16x3)
    f32x4 a0 = {0.f, 0.f, 0.f, 0.f};
    f32x4 a1 = a0, a2 = a0;
    const int rbase = l15 * 4096;
    const int sw = (l15 & 7) << 4;
    #pragma unroll
    for (int ks = 0; ks < 8; ++ks) {
      int bo = (wave * 32 + ks * 4 + l4) * 32;
      uint4 pA = *(const uint4*)(ldsP + rbase + (bo ^ sw));
      uint4 pB = *(const uint4*)(ldsP + rbase + ((bo + 16) ^ sw));
      u32 c0_[8] = {pA.x, pA.y, pA.z, pA.w, pB.x, pB.y, pB.z, pB.w};
      union { u32 u[4]; bf16x8 v; } ah, al;
      #pragma unroll
      for (int j = 0; j < 4; ++j) {
        u32 c0 = c0_[2 * j], c1 = c0_[2 * j + 1];
        ah.u[j] = (c0 >> 16) | (c1 & 0xFFFF0000u);
        al.u[j] = (c0 & 0xFFFFu) | (c1 << 16);
      }
      a0 = MFMA(ah.v, Wh[0][ks], a0); a0 = MFMA(ah.v, Wl[0][ks], a0); a0 = MFMA(al.v, Wh[0][ks], a0);
      a1 = MFMA(ah.v, Wh[1][ks], a1); a1 = MFMA(ah.v, Wl[1][ks], a1); a1 = MFMA(al.v, Wh[1][ks], a1);
      a2 = MFMA(ah.v, Wh[2][ks], a2); a2 = MFMA(ah.v, Wl[2][ks], a2); a2 = MFMA(al.v, Wh[2][ks], a2);
    }

    // ---- cross-wave K-reduce
    if (wave != 0) {
      int rb = (wave - 1) * 3072;
      *(f32x4*)(ldsRed + rb + 0 * 1024 + lane * 16) = a0;
      *(f32x4*)(ldsRed + rb + 1 * 1024 + lane * 16) = a1;
      *(f32x4*)(ldsRed + rb + 2 * 1024 + lane * 16) = a2;
    }
    __syncthreads();

    if (wave == 0) {
      #pragma unroll
      for (int w = 1; w < 4; ++w) {
        int rb = (w - 1) * 3072;
        a0 += *(const f32x4*)(ldsRed + rb + 0 * 1024 + lane * 16);
        a1 += *(const f32x4*)(ldsRed + rb + 1 * 1024 + lane * 16);
        a2 += *(const f32x4*)(ldsRed + rb + 2 * 1024 + lane * 16);
      }
      const int t = t0 + tl;
      #pragma unroll
      for (int r = 0; r < 4; ++r) {
        int b = brow + r;
        float hz = a0[r] + bz, hr = a1[r] + br, hhv = a2[r] + bh;
        float z  = 1.f / (1.f + __expf(-(pxz[r] + hz)));
        float rg = 1.f / (1.f + __expf(-(pxr[r] + hr)));
        float ct = pxh[r] + rg * hhv;
        float e2 = __expf(2.f * ct);
        float cand = 1.f - 2.f / (e2 + 1.f);  // tanh(ct)
        float hnew = (t < lens[r]) ? (z * phold[r] + (1.f - z) * cand) : phold[r];
        u16 nhi = f2bf(hnew);
        u16 nlo = f2bf(hnew - bf2f(nhi));
        u32 pk = ((u32)nhi << 16) | nlo;
        size_t crow = ((size_t)tl * B_ + b) * H_ + ccol;
        if (Hh) { Hh[crow] = nhi; Hl[crow] = nlo; }  // plain: for next GEMM
        __hip_atomic_store(Hpk + (size_t)tl * B_ * H_ + (size_t)b * H_ + ccol,
                           pk, __ATOMIC_RELAXED, __HIP_MEMORY_SCOPE_AGENT);
        if (outF32) outF32[((size_t)b * T_ + t) * H_ + ccol] = hnew;
        if (tl == TC_ - 1) Spk[(size_t)b * H_ + ccol] = pk;  // next dispatch
      }
    }

    // ---- per-mtile flag: vmcnt ack, relaxed add, relaxed polls (no fences)
    if (tl != TC_ - 1) {
      if (tid == 0) {
        asm volatile("s_waitcnt vmcnt(0)" ::: "memory");
        __hip_atomic_fetch_add(bar, 1u, __ATOMIC_RELAXED, __HIP_MEMORY_SCOPE_AGENT);
        unsigned tgt = 64u * (unsigned)(tl + 1);
        while (__hip_atomic_load(bar, __ATOMIC_RELAXED, __HIP_MEMORY_SCOPE_AGENT) < tgt)
          __builtin_amdgcn_s_sleep(1);
      }
      __syncthreads();
    }
  }
}

// ----------------------------------------------------------------- launch
extern "C" void kernel_launch(void* const* d_in, const int* in_sizes, int n_in,
                              void* d_out, int out_size, void* d_ws, size_t ws_size,
                              hipStream_t stream) {
  (void)in_sizes; (void)n_in; (void)out_size; (void)ws_size;
  const float* x      = (const float*)d_in[0];
  const int* lengths  = (const int*)d_in[1];
  const float* k0     = (const float*)d_in[2];
  const float* rk0    = (const float*)d_in[3];
  const float* b0     = (const float*)d_in[4];
  const float* k1     = (const float*)d_in[5];
  const float* rk1    = (const float*)d_in[6];
  const float* b1     = (const float*)d_in[7];
  float* out = (float*)d_out;
  char* ws = (char*)d_ws;

  const size_t WB = (size_t)N3_ * 1024 * 2;      // 6,291,456 B
  const size_t XB = (size_t)MROWS_ * 1024 * 2;   // 4,194,304 B
  size_t off = 0;
  u16* k0Th  = (u16*)(ws + off); off += WB;
  u16* k0Tl  = (u16*)(ws + off); off += WB;
  u16* rk0Th = (u16*)(ws + off); off += WB;
  u16* rk0Tl = (u16*)(ws + off); off += WB;
  u16* k1Th  = (u16*)(ws + off); off += WB;
  u16* k1Tl  = (u16*)(ws + off); off += WB;
  u16* rk1Th = (u16*)(ws + off); off += WB;
  u16* rk1Tl = (u16*)(ws + off); off += WB;
  u16* XCh   = (u16*)(ws + off); off += XB;      // aliased by Hpk during rec
  u16* XCl   = (u16*)(ws + off); off += XB;
  float* MX  = (float*)(ws + off); off += (size_t)MROWS_ * N3_ * 4;  // 25.2 MB
  u16* H0h   = (u16*)(ws + off); off += XB;
  u16* H0l   = (u16*)(ws + off); off += XB;
  u32* Spk0  = (u32*)(ws + off); off += (size_t)B_ * H_ * 4;
  u32* Spk1  = (u32*)(ws + off); off += (size_t)B_ * H_ * 4;
  unsigned* bars = (unsigned*)(ws + off); off += (size_t)2 * NCH_ * 256 * 4;
  u32* Hpk = (u32*)XCh;  // [TC][B][H] u32 = 8.4 MB, aliases XCh+XCl (dead in rec)
  // total ~85 MB

  init_ws<<<256, 256, 0, stream>>>(Spk0, Spk1, bars);

  dim3 tb(32, 8), tg(96, 32);
  transpose_split<<<tg, tb, 0, stream>>>(k0,  k0Th,  k0Tl);
  transpose_split<<<tg, tb, 0, stream>>>(rk0, rk0Th, rk0Tl);
  transpose_split<<<tg, tb, 0, stream>>>(k1,  k1Th,  k1Tl);
  transpose_split<<<tg, tb, 0, stream>>>(rk1, rk1Th, rk1Tl);

  for (int c = 0; c < NCH_; ++c) {
    int t0 = c * TC_;
    split_x_chunk<<<2048, 256, 0, stream>>>(x, t0, XCh, XCl);
    gemm_bf16x3<<<dim3(24, 16), 256, 0, stream>>>(XCh, XCl, k0Th, k0Tl, b0, MX);
    gru_rec_v3<<<256, 256, 0, stream>>>(MX, rk0Th, rk0Tl, b0 + N3_, lengths,
                                        Spk0, Hpk, H0h, H0l, nullptr,
                                        bars + (size_t)c * 256, t0);
    gemm_bf16x3<<<dim3(24, 16), 256, 0, stream>>>(H0h, H0l, k1Th, k1Tl, b1, MX);
    gru_rec_v3<<<256, 256, 0, stream>>>(MX, rk1Th, rk1Tl, b1 + N3_, lengths,
                                        Spk1, Hpk, (u16*)nullptr, (u16*)nullptr, out,
                                        bars + (size_t)(NCH_ + c) * 256, t0);
  }
}